// Round 1
// baseline (2579.865 us; speedup 1.0000x reference)
//
#include <hip/hip_runtime.h>

// CIN (xDeepFM-style) fused kernel, fp32 baseline.
// B=8192, F0=39, D=16, layers: C={1521,2496,2496}, L=128.
// Block = 256 threads, NB=8 batch elems/block (M-tile = NB*D = 128 rows).
// Per-thread 8x8 micro-tile: rows m = trow*8..+8 (nb = trow>>1, d = (trow&1)*8+mi),
// cols n = {tcol*4+q, 64+tcol*4+q}.  KT=16 filter k-tile staged in LDS.
// LDS ~59.5 KB -> 2 blocks/CU; __launch_bounds__(256,2) allows up to 256 VGPR.

#define F0 39
#define DD 16
#define NB 8
#define KT 16

__global__ __launch_bounds__(256, 2) void cin_kernel(
    const float* __restrict__ xin,   // (B, 624)
    const float* __restrict__ f0g,   // (1521, 128)
    const float* __restrict__ f1g,   // (2496, 128)
    const float* __restrict__ f2g,   // (2496, 128)
    const float* __restrict__ wnn,   // (256)
    const float* __restrict__ bnn,   // (1)
    float* __restrict__ out)         // (B)
{
    __shared__ float x0s[NB * F0 * DD];   // [nb][i][d]  4992 f = 19968 B
    __shared__ float hid[NB * 64 * DD];   // [nb][j][d]  8192 f = 32768 B
    __shared__ float ftile[KT * 128];     // [jj][n]     2048 f =  8192 B
    __shared__ float outacc[NB];

    const int t    = threadIdx.x;
    const int tcol = t & 15;
    const int trow = t >> 4;
    const int nb   = trow >> 1;
    const int d0   = (trow & 1) * 8;
    const int b0   = blockIdx.x * NB;

    // stage x0 for this block's 8 batch rows (624 floats = 156 float4 each)
    for (int u = t; u < NB * 156; u += 256) {
        int nbi = u / 156;
        int e   = u - nbi * 156;
        *(float4*)&x0s[nbi * 624 + e * 4] =
            *(const float4*)&xin[(size_t)(b0 + nbi) * 624 + e * 4];
    }
    if (t < NB) outacc[t] = 0.0f;
    __syncthreads();

    for (int layer = 0; layer < 3; ++layer) {
        float acc[8][8];
        #pragma unroll
        for (int mi = 0; mi < 8; ++mi)
            #pragma unroll
            for (int ni = 0; ni < 8; ++ni) acc[mi][ni] = 0.0f;

        const float* Fg      = (layer == 0) ? f0g : ((layer == 1) ? f1g : f2g);
        const int    cstride = (layer == 0) ? F0 : 64;
        const int    jmax    = (layer == 0) ? F0 : 64;
        const float  xscale  = (layer == 0) ? 2.0f : 1.0f;  // triu mask *2, j>i only
        const float* hbase   = (layer == 0) ? &x0s[nb * F0 * DD] : &hid[nb * 64 * DD];

        for (int i = 0; i < F0; ++i) {
            const int jstart = (layer == 0) ? (i + 1) : 0;  // strict upper triangle
            // x0[b, i, d0..d0+8] for this thread's 8 rows (same nb, fixed i)
            float xr[8];
            {
                float4 xa = *(const float4*)&x0s[nb * F0 * DD + i * DD + d0];
                float4 xb = *(const float4*)&x0s[nb * F0 * DD + i * DD + d0 + 4];
                xr[0] = xscale * xa.x; xr[1] = xscale * xa.y;
                xr[2] = xscale * xa.z; xr[3] = xscale * xa.w;
                xr[4] = xscale * xb.x; xr[5] = xscale * xb.y;
                xr[6] = xscale * xb.z; xr[7] = xscale * xb.w;
            }
            for (int j0 = jstart; j0 < jmax; j0 += KT) {
                const int jcount = min(KT, jmax - j0);
                const int c0     = i * cstride + j0;
                __syncthreads();   // previous ftile fully consumed
                for (int u = t; u < jcount * 32; u += 256) {
                    int jj = u >> 5;
                    int n4 = u & 31;
                    *(float4*)&ftile[jj * 128 + n4 * 4] =
                        *(const float4*)&Fg[(size_t)(c0 + jj) * 128 + n4 * 4];
                }
                __syncthreads();

                auto body = [&](int jj) {
                    const float* hp = hbase + (j0 + jj) * DD + d0;
                    float4 h1 = *(const float4*)hp;
                    float4 h2 = *(const float4*)(hp + 4);
                    const float* fp = &ftile[jj * 128 + tcol * 4];
                    float4 fa = *(const float4*)fp;
                    float4 fb = *(const float4*)(fp + 64);
                    float hv[8] = {h1.x, h1.y, h1.z, h1.w, h2.x, h2.y, h2.z, h2.w};
                    float fv[8] = {fa.x, fa.y, fa.z, fa.w, fb.x, fb.y, fb.z, fb.w};
                    #pragma unroll
                    for (int mi = 0; mi < 8; ++mi) {
                        float z = xr[mi] * hv[mi];
                        #pragma unroll
                        for (int ni = 0; ni < 8; ++ni)
                            acc[mi][ni] = fmaf(z, fv[ni], acc[mi][ni]);
                    }
                };
                if (jcount == KT) {
                    #pragma unroll
                    for (int jj = 0; jj < KT; ++jj) body(jj);
                } else {
                    for (int jj = 0; jj < jcount; ++jj) body(jj);
                }
            }
        }

        __syncthreads();   // all k-loop LDS reads done before hid overwrite

        // ReLU in registers
        float r[8][8];
        #pragma unroll
        for (int mi = 0; mi < 8; ++mi)
            #pragma unroll
            for (int ni = 0; ni < 8; ++ni)
                r[mi][ni] = fmaxf(acc[mi][ni], 0.0f);

        // next_hidden = curr[:, 0:64, :]  (cols tcol*4+q are always < 64)
        if (layer < 2) {
            #pragma unroll
            for (int q = 0; q < 4; ++q) {
                int n = tcol * 4 + q;
                #pragma unroll
                for (int mi = 0; mi < 8; ++mi)
                    hid[nb * 64 * DD + n * DD + d0 + mi] = r[mi][q];
            }
        }

        // rs[cat] = sum_d curr; lanes trow/trow^1 hold d0=0/8 halves of same (nb,n)
        float s[8];
        #pragma unroll
        for (int ni = 0; ni < 8; ++ni) {
            float v = 0.0f;
            #pragma unroll
            for (int mi = 0; mi < 8; ++mi) v += r[mi][ni];
            s[ni] = v + __shfl_xor(v, 16, 64);
        }
        if ((trow & 1) == 0) {
            float contrib = 0.0f;
            if (layer == 2) {
                // direct = all 128 cols: cat = 128 + n
                #pragma unroll
                for (int q = 0; q < 4; ++q)
                    contrib += s[q]     * (1.0f + wnn[128 + tcol * 4 + q]);
                #pragma unroll
                for (int q = 0; q < 4; ++q)
                    contrib += s[4 + q] * (1.0f + wnn[192 + tcol * 4 + q]);
            } else {
                // direct = cols 64..127: cat = (layer==0 ? n-64 : n)
                const int cbase = (layer == 0) ? 0 : 64;
                #pragma unroll
                for (int q = 0; q < 4; ++q)
                    contrib += s[4 + q] * (1.0f + wnn[cbase + tcol * 4 + q]);
            }
            atomicAdd(&outacc[nb], contrib);
        }
        __syncthreads();   // hid writes + outacc visible before next layer / output
    }

    if (t < NB) out[b0 + t] = outacc[t] + bnn[0];
}

extern "C" void kernel_launch(void* const* d_in, const int* in_sizes, int n_in,
                              void* d_out, int out_size, void* d_ws, size_t ws_size,
                              hipStream_t stream) {
    const float* xin = (const float*)d_in[0];
    const float* f0g = (const float*)d_in[1];
    const float* f1g = (const float*)d_in[2];
    const float* f2g = (const float*)d_in[3];
    const float* wnn = (const float*)d_in[4];
    const float* bnn = (const float*)d_in[5];
    float* out = (float*)d_out;

    const int B = in_sizes[0] / (F0 * DD);   // 8192
    dim3 grid(B / NB), block(256);
    cin_kernel<<<grid, block, 0, stream>>>(xin, f0g, f1g, f2g, wnn, bnn, out);
}

// Round 2
// 290.555 us; speedup vs baseline: 8.8791x; 8.8791x over previous
//
#include <hip/hip_runtime.h>

// CIN fused kernel, round 2: f16 MFMA (mfma_f32_16x16x32_f16).
// GEMM view: M = B*16 = 131072 rows (m = batch*16 + d), N = 128, K = i*64+j
// (layer-0 K unified to 64-padded j with zero-padded filter + triangular mask
// folded into A as x_i*x_j*{0,2}).
// Block = 256 thr (4 waves), 8 batches (M-tile 128). Wave (mg,ng) 2x2 split:
// 4 m-tiles x 4 n-tiles = 16 mfma per K=32 chunk, acc = 16 x float4.
// B-fragments: pre-swizzled f16 filters in ws (prep kernel), loaded straight
// from global/L2 as one dwordx4 per frag -> NO LDS filter tile, NO K-loop
// barriers. A-fragments: hT[nb][d][72] f16 in LDS (144 B stride: 16B-aligned,
// 2-way bank alias = free), 1 ds_read_b128 + 1 x-scalar + v_pk_mul_f16.

#define F0N 39
#define NCH 78                    // K chunks per layer: 2496/32
#define LAYER_HALVES (NCH * 4096) // fprep halves per layer

typedef _Float16 half8 __attribute__((ext_vector_type(8)));
typedef float f32x4 __attribute__((ext_vector_type(4)));

// ---- prep: swizzle filters into MFMA B-fragment order, f16 ----
// fprep[l][c][nt][lane][j] = F_l[row(kg), nt*16 + (lane&15)], kg = c*32 + (lane>>4)*8 + j
// layer 0: row = i*39+j if j<39 else ZERO (j = kg&63, i = kg>>6); layers 1,2: row = kg.
__global__ void prep_kernel(const float* __restrict__ f0,
                            const float* __restrict__ f1,
                            const float* __restrict__ f2,
                            _Float16* __restrict__ fprep) {
    int idx = blockIdx.x * blockDim.x + threadIdx.x;
    if (idx >= 3 * LAYER_HALVES) return;
    int j    = idx & 7;
    int lane = (idx >> 3) & 63;
    int nt   = (idx >> 9) & 7;
    int rem  = idx >> 12;        // l*NCH + c
    int c    = rem % NCH;
    int l    = rem / NCH;
    int kg   = c * 32 + ((lane >> 4) << 3) + j;
    int fi   = kg >> 6;
    int fj   = kg & 63;
    int n    = (nt << 4) + (lane & 15);
    float v = 0.0f;
    if (l == 0) {
        if (fj < F0N) v = f0[(fi * F0N + fj) * 128 + n];
    } else {
        const float* f = (l == 1) ? f1 : f2;
        v = f[(size_t)kg * 128 + n];
    }
    fprep[idx] = (_Float16)v;
}

__global__ __launch_bounds__(256, 3) void cin_mfma(
    const float* __restrict__ xin,     // (B, 624) fp32
    const _Float16* __restrict__ fprep,
    const float* __restrict__ wnn,     // (256)
    const float* __restrict__ bnn,     // (1)
    float* __restrict__ out)           // (B)
{
    __shared__ _Float16 hT[8 * 16 * 72] __attribute__((aligned(16)));  // [nb][d][j pad72]
    __shared__ _Float16 xs[8 * 16 * 40] __attribute__((aligned(16)));  // [nb][d][i pad40]
    __shared__ float outacc[8];

    const int t    = threadIdx.x;
    const int wave = t >> 6;
    const int lane = t & 63;
    const int quad = lane >> 4;
    const int nl   = lane & 15;
    const int mg   = wave >> 1;   // m-group: batches mg*4 .. +4
    const int ng   = wave & 1;    // n-half:  cols ng*64 .. +64
    const int b0   = blockIdx.x * 8;

    // zero hT (incl. j=39..71 pad) and xs
    for (int u = t; u < 1152; u += 256) ((uint4*)hT)[u] = uint4{0, 0, 0, 0};
    for (int u = t; u < 640;  u += 256) ((uint4*)xs)[u] = uint4{0, 0, 0, 0};
    if (t < 8) outacc[t] = 0.0f;
    __syncthreads();

    // stage x0 -> hT (layer-0 hidden) and xs (x_i side, persistent)
    for (int u = t; u < 8 * F0N; u += 256) {
        int nb = u / F0N;
        int i  = u - nb * F0N;
        const float* src = xin + (size_t)(b0 + nb) * 624 + i * 16;
        #pragma unroll
        for (int q = 0; q < 4; ++q) {
            float4 v = *(const float4*)(src + q * 4);
            int d = q * 4;
            hT[(nb * 16 + d + 0) * 72 + i] = (_Float16)v.x;
            hT[(nb * 16 + d + 1) * 72 + i] = (_Float16)v.y;
            hT[(nb * 16 + d + 2) * 72 + i] = (_Float16)v.z;
            hT[(nb * 16 + d + 3) * 72 + i] = (_Float16)v.w;
            xs[(nb * 16 + d + 0) * 40 + i] = (_Float16)v.x;
            xs[(nb * 16 + d + 1) * 40 + i] = (_Float16)v.y;
            xs[(nb * 16 + d + 2) * 40 + i] = (_Float16)v.z;
            xs[(nb * 16 + d + 3) * 40 + i] = (_Float16)v.w;
        }
    }
    __syncthreads();

    const int jbq = quad << 3;    // this quad's k-run start within a 32-chunk

    for (int layer = 0; layer < 3; ++layer) {
        f32x4 acc[4][4];
        #pragma unroll
        for (int mm = 0; mm < 4; ++mm)
            #pragma unroll
            for (int tt = 0; tt < 4; ++tt)
                acc[mm][tt] = (f32x4){0.f, 0.f, 0.f, 0.f};

        const _Float16* fpl = fprep + (size_t)layer * LAYER_HALVES;

        for (int c = 0; c < NCH; ++c) {
            const int i    = c >> 1;
            const int jb_c = ((c & 1) << 5) + jbq;   // j of frag element 0
            // layer-0 chunks with empty (j>i, j<39) intersection: skip
            if (layer == 0 && ((c & 1) ? (i >= 38) : (i >= 31))) continue;

            // B-fragments straight from global (L2-resident, frag-ordered)
            half8 Bf[4];
            #pragma unroll
            for (int tt = 0; tt < 4; ++tt) {
                int ntg = ng * 4 + tt;
                Bf[tt] = *(const half8*)(fpl + (((c * 8 + ntg) * 64 + lane) << 3));
            }

            // A-fragments: A[m=nl][k=quad*8+j] = x[nb,i,nl] * h[nb,j,nl] (*mask)
            const _Float16* hp = &hT[nl * 72 + jb_c];
            const _Float16* xp = &xs[nl * 40 + i];
            half8 Af[4];
            if (layer == 0) {
                half8 m8;
                #pragma unroll
                for (int j = 0; j < 8; ++j)
                    m8[j] = (jb_c + j > i) ? (_Float16)2.0f : (_Float16)0.0f;
                #pragma unroll
                for (int mm = 0; mm < 4; ++mm) {
                    int nb = mg * 4 + mm;
                    half8 hv = *(const half8*)(hp + nb * 1152);
                    _Float16 xv = xp[nb * 640];
                    Af[mm] = hv * (m8 * xv);
                }
            } else {
                #pragma unroll
                for (int mm = 0; mm < 4; ++mm) {
                    int nb = mg * 4 + mm;
                    half8 hv = *(const half8*)(hp + nb * 1152);
                    _Float16 xv = xp[nb * 640];
                    Af[mm] = hv * xv;
                }
            }

            #pragma unroll
            for (int mm = 0; mm < 4; ++mm)
                #pragma unroll
                for (int tt = 0; tt < 4; ++tt)
                    acc[mm][tt] = __builtin_amdgcn_mfma_f32_16x16x32_f16(
                        Af[mm], Bf[tt], acc[mm][tt], 0, 0, 0);
        }

        __syncthreads();   // all hT reads for this layer done

        // epilogue: relu, hidden write (cols<64), weighted rs readout
        const bool docontrib = (layer == 2) || (ng == 1);
        const int  catbase   = (layer == 2) ? 128 : ((layer == 0) ? -64 : 0);
        float wv[4];
        #pragma unroll
        for (int tt = 0; tt < 4; ++tt) {
            int ngl = (ng * 4 + tt) * 16 + nl;
            wv[tt] = docontrib ? (1.0f + wnn[catbase + ngl]) : 0.0f;
        }
        #pragma unroll
        for (int mm = 0; mm < 4; ++mm) {
            int nb = mg * 4 + mm;
            float cm = 0.0f;
            #pragma unroll
            for (int tt = 0; tt < 4; ++tt) {
                f32x4 a = acc[mm][tt];
                float r0 = fmaxf(a[0], 0.f), r1 = fmaxf(a[1], 0.f);
                float r2 = fmaxf(a[2], 0.f), r3 = fmaxf(a[3], 0.f);
                if (layer < 2 && ng == 0) {
                    // C layout: row(d) = quad*4+r, col(j) = nl; cols 0..63 = next hidden
                    _Float16* hw = &hT[(nb * 16 + (quad << 2)) * 72 + (tt * 16 + nl)];
                    hw[0]       = (_Float16)r0;
                    hw[72]      = (_Float16)r1;
                    hw[144]     = (_Float16)r2;
                    hw[216]     = (_Float16)r3;
                }
                float s = r0 + r1 + r2 + r3;          // partial d-sum (4 of 16)
                s += __shfl_xor(s, 16, 64);
                s += __shfl_xor(s, 32, 64);           // full d-sum, all quads equal
                cm = fmaf(s, wv[tt], cm);
            }
            cm += __shfl_xor(cm, 1, 64);
            cm += __shfl_xor(cm, 2, 64);
            cm += __shfl_xor(cm, 4, 64);
            cm += __shfl_xor(cm, 8, 64);
            if (lane == 0) atomicAdd(&outacc[nb], cm);
        }
        __syncthreads();   // hidden + outacc visible
    }

    if (t < 8) out[b0 + t] = outacc[t] + bnn[0];
}

extern "C" void kernel_launch(void* const* d_in, const int* in_sizes, int n_in,
                              void* d_out, int out_size, void* d_ws, size_t ws_size,
                              hipStream_t stream) {
    const float* xin = (const float*)d_in[0];
    const float* f0g = (const float*)d_in[1];
    const float* f1g = (const float*)d_in[2];
    const float* f2g = (const float*)d_in[3];
    const float* wnn = (const float*)d_in[4];
    const float* bnn = (const float*)d_in[5];
    float* out = (float*)d_out;
    _Float16* fprep = (_Float16*)d_ws;   // 3*78*8192 B = 1.87 MB

    int prep_elems = 3 * LAYER_HALVES;
    prep_kernel<<<(prep_elems + 255) / 256, 256, 0, stream>>>(f0g, f1g, f2g, fprep);

    const int B = in_sizes[0] / 624;     // 8192
    cin_mfma<<<B / 8, 256, 0, stream>>>(xin, fprep, wnn, bnn, out);
}